// Round 6
// baseline (169.231 us; speedup 1.0000x reference)
//
#include <hip/hip_runtime.h>
#include <hip/hip_bf16.h>

#define B_DIM 64
#define I_DIM 16384
#define O_DIM 1024
#define K_BASIS 5
#define H_DIM 16
#define IK (I_DIM * K_BASIS)   // 81920

typedef __attribute__((ext_vector_type(8))) short short8;
typedef __attribute__((ext_vector_type(4))) float f32x4;

// ---------------------------------------------------------------------------
// Kernel 1: basis[b][i] = w2[i%5] . silu(x[b][i]*w1[i%5] + b1[i%5]) + b2[i%5]
// ---------------------------------------------------------------------------
__global__ __launch_bounds__(256)
void basis_kernel(const float* __restrict__ x,
                  const float* __restrict__ w1,
                  const float* __restrict__ b1,
                  const float* __restrict__ w2,
                  const float* __restrict__ b2,
                  __hip_bfloat16* __restrict__ basis) {
    __shared__ float4 pk[K_BASIS][H_DIM + 1];   // {w1,b1,w2,0}
    __shared__ float pb2[K_BASIS];
    const int t = threadIdx.x;
    if (t < K_BASIS * H_DIM) {
        const int k = t / H_DIM, h = t % H_DIM;
        pk[k][h] = float4{w1[t], b1[t], w2[t], 0.f};
        if (t < K_BASIS) pb2[t] = b2[t];
    }
    __syncthreads();

    const int gid = blockIdx.x * 256 + t;
    const int i8 = gid % (I_DIM / 8);
    const int b  = gid / (I_DIM / 8);
    const int i0 = i8 * 8;

    const float4* xp = reinterpret_cast<const float4*>(x + (size_t)b * I_DIM + i0);
    float4 xa = xp[0];
    float4 xb = xp[1];
    float xs[8] = {xa.x, xa.y, xa.z, xa.w, xb.x, xb.y, xb.z, xb.w};

    __hip_bfloat16 res[8];
#pragma unroll
    for (int j = 0; j < 8; ++j) {
        const int idx = (i0 + j) % K_BASIS;
        const float xv = xs[j];
        float acc = 0.f;
#pragma unroll
        for (int h = 0; h < H_DIM; ++h) {
            const float4 p = pk[idx][h];
            float a = fmaf(xv, p.x, p.y);
            float s = a * __builtin_amdgcn_rcpf(1.f + __expf(-a));   // silu
            acc = fmaf(s, p.z, acc);
        }
        res[j] = __float2bfloat16(acc + pb2[idx]);
    }
    *reinterpret_cast<short8*>(basis + (size_t)b * I_DIM + i0) =
        *reinterpret_cast<short8*>(res);
}

// ---------------------------------------------------------------------------
// Kernel 2: out[64,1024] = basis[64,16384] @ Wsum[16384,1024]
// Round-5 skeleton; DENSE staging (each wave-instruction = 1024 B contiguous),
// raw f32 W in LDS (40 KiB x2), XOR-swizzled (u ^= row&7 in 16B units) so the
// fold-on-read (lane=col, row stride 2560 B) is bank-conflict-free.
// ---------------------------------------------------------------------------
#define NT 16
#define CI 128
#define KSPLIT 8
#define NCHUNK (I_DIM / KSPLIT / CI)   // 16
#define ROWB (CI * K_BASIS * 4)        // 2560 B per o-row per chunk
#define BUFB (NT * ROWB)               // 40960 B per chunk buffer

#define PUBLISH() do {                                                  \
        asm volatile("s_waitcnt lgkmcnt(0)" ::: "memory");              \
        __builtin_amdgcn_s_barrier();                                   \
        asm volatile("" ::: "memory");                                  \
    } while (0)

__global__ __launch_bounds__(256, 2)
void kan_gemm(const float* __restrict__ W,
              const __hip_bfloat16* __restrict__ basis,
              float* __restrict__ out) {
    __shared__ float4 smem[2 * BUFB / 16];              // 80 KiB
    char* const Bs0 = reinterpret_cast<char*>(smem);
    char* const Bs1 = Bs0 + BUFB;
    float* const red = reinterpret_cast<float*>(smem);  // epilogue [4][1024]

    const int t    = threadIdx.x;
    const int lane = t & 63;
    const int wv   = t >> 6;          // k-slice 0..3
    const int col  = lane & 15;
    const int kgrp = lane >> 4;
    const int o0   = blockIdx.x * NT;
    const int i00  = blockIdx.y * (CI * NCHUNK);        // 2048-i band

    // dense staging: slot q -> flat = t + 256q; row = flat/160, u = flat%160
    // (u in float4 units; 160 per row). LDS stores [row][u ^ (row&7)] = W[row][u].
    int goff[10], loff[10];
#pragma unroll
    for (int q = 0; q < 10; ++q) {
        const int flat = t + 256 * q;
        const int row  = flat / 160;
        const int u    = flat - row * 160;
        goff[q] = row * (IK * 4) + u * 16;                       // bytes
        loff[q] = (row * 160 + (u ^ (row & 7))) * 16;            // bytes
    }
    // fold-read addrs: lane reads W[col][u_q], u_q = wv*40 + kgrp*10 + q
    int rdoff[10];
#pragma unroll
    for (int q = 0; q < 10; ++q)
        rdoff[q] = (col * 160 + ((wv * 40 + kgrp * 10 + q) ^ (col & 7))) * 16;

    const char* const wbase = reinterpret_cast<const char*>(W)
                            + (size_t)o0 * (IK * 4) + (size_t)i00 * 20;
    const __hip_bfloat16* const abase = basis + i00 + wv * 32 + kgrp * 8;

    float4 ra[10], rb[10];
    short8 af[4];

#define ISSUE(R, c) do {                                                \
        _Pragma("unroll") for (int q = 0; q < 10; ++q)                  \
            R[q] = *reinterpret_cast<const float4*>(                    \
                wbase + (size_t)(c) * ROWB + goff[q]);                  \
    } while (0)

#define COMMIT(BS, R) do {                                              \
        _Pragma("unroll") for (int q = 0; q < 10; ++q)                  \
            *reinterpret_cast<float4*>((BS) + loff[q]) = R[q];          \
    } while (0)

#define AFLOAD(c) do {                                                  \
        _Pragma("unroll") for (int m = 0; m < 4; ++m)                   \
            af[m] = *reinterpret_cast<const short8*>(                   \
                abase + (size_t)(m * 16 + col) * I_DIM + (c) * CI);     \
    } while (0)

#define COMPUTE(BS) do {                                                \
        float ws[8] = {0.f,0.f,0.f,0.f,0.f,0.f,0.f,0.f};                \
        _Pragma("unroll") for (int q = 0; q < 10; ++q) {                \
            const float4 v = *reinterpret_cast<const float4*>(          \
                (BS) + rdoff[q]);                                       \
            ws[(4*q+0)/5] += v.x;                                       \
            ws[(4*q+1)/5] += v.y;                                       \
            ws[(4*q+2)/5] += v.z;                                       \
            ws[(4*q+3)/5] += v.w;                                       \
        }                                                               \
        __hip_bfloat16 wb8[8];                                          \
        _Pragma("unroll") for (int u2 = 0; u2 < 8; ++u2)                \
            wb8[u2] = __float2bfloat16(ws[u2]);                         \
        const short8 bfr = *reinterpret_cast<short8*>(wb8);             \
        _Pragma("unroll") for (int m = 0; m < 4; ++m)                   \
            acc[m] = __builtin_amdgcn_mfma_f32_16x16x32_bf16(           \
                af[m], bfr, acc[m], 0, 0, 0);                           \
    } while (0)

    f32x4 acc[4] = {f32x4{0,0,0,0}, f32x4{0,0,0,0}, f32x4{0,0,0,0}, f32x4{0,0,0,0}};

    // prologue: chunks 0,1 in flight; publish chunk 0 in Bs0
    ISSUE(ra, 0);
    ISSUE(rb, 1);
    COMMIT(Bs0, ra);
    PUBLISH();

#pragma unroll
    for (int cc = 0; cc < NCHUNK; cc += 2) {
        // ---- even chunk cc (in Bs0) ----
        AFLOAD(cc);
        __builtin_amdgcn_sched_barrier(0);
        if (cc + 2 < NCHUNK) ISSUE(ra, cc + 2);
        COMMIT(Bs1, rb);                        // chunk cc+1 -> Bs1 (counted vmcnt)
        COMPUTE(Bs0);
        PUBLISH();
        // ---- odd chunk cc+1 (in Bs1) ----
        AFLOAD(cc + 1);
        __builtin_amdgcn_sched_barrier(0);
        if (cc + 3 < NCHUNK) ISSUE(rb, cc + 3);
        if (cc + 2 < NCHUNK) COMMIT(Bs0, ra);   // chunk cc+2 -> Bs0
        COMPUTE(Bs1);
        if (cc + 2 < NCHUNK) PUBLISH();
    }
    PUBLISH();                                  // all LDS reads done before reuse

    // ---- epilogue: cross-wave reduce in LDS, then 4 atomics/thread ----
#pragma unroll
    for (int m = 0; m < 4; ++m)
#pragma unroll
        for (int j = 0; j < 4; ++j)
            red[wv * 1024 + (m * 16 + kgrp * 4 + j) * 16 + col] = acc[m][j];
    PUBLISH();

    const float4 v0 = *reinterpret_cast<const float4*>(&red[0 * 1024 + t * 4]);
    const float4 v1 = *reinterpret_cast<const float4*>(&red[1 * 1024 + t * 4]);
    const float4 v2 = *reinterpret_cast<const float4*>(&red[2 * 1024 + t * 4]);
    const float4 v3 = *reinterpret_cast<const float4*>(&red[3 * 1024 + t * 4]);
    const float s[4] = {v0.x + v1.x + v2.x + v3.x, v0.y + v1.y + v2.y + v3.y,
                        v0.z + v1.z + v2.z + v3.z, v0.w + v1.w + v2.w + v3.w};
    const int brow = t >> 2;
    const int c4   = (t & 3) * 4;
#pragma unroll
    for (int k = 0; k < 4; ++k)
        atomicAdd(&out[(size_t)brow * O_DIM + o0 + c4 + k], s[k]);

#undef ISSUE
#undef COMMIT
#undef AFLOAD
#undef COMPUTE
}

// ---------------------------------------------------------------------------
extern "C" void kernel_launch(void* const* d_in, const int* in_sizes, int n_in,
                              void* d_out, int out_size, void* d_ws, size_t ws_size,
                              hipStream_t stream) {
    const float* x  = (const float*)d_in[0];
    const float* w1 = (const float*)d_in[1];
    const float* b1 = (const float*)d_in[2];
    const float* w2 = (const float*)d_in[3];
    const float* b2 = (const float*)d_in[4];
    const float* W  = (const float*)d_in[5];
    float* out = (float*)d_out;
    __hip_bfloat16* basis = (__hip_bfloat16*)d_ws;   // 64*16384*2 = 2 MiB

    hipMemsetAsync(d_out, 0, (size_t)out_size * sizeof(float), stream);

    basis_kernel<<<dim3((B_DIM * I_DIM / 8) / 256), dim3(256), 0, stream>>>(
        x, w1, b1, w2, b2, basis);

    dim3 grid(O_DIM / NT, KSPLIT);   // (64, 8) = 512 WGs = 2/CU
    kan_gemm<<<grid, dim3(256), 0, stream>>>(W, basis, out);
}

// Round 7
// 143.670 us; speedup vs baseline: 1.1779x; 1.1779x over previous
//
#include <hip/hip_runtime.h>
#include <hip/hip_bf16.h>

#define B_DIM 64
#define I_DIM 16384
#define O_DIM 1024
#define K_BASIS 5
#define H_DIM 16
#define IK (I_DIM * K_BASIS)   // 81920

typedef __attribute__((ext_vector_type(8))) short short8;
typedef __attribute__((ext_vector_type(4))) float f32x4;

// ---------------------------------------------------------------------------
// Kernel 1: basis[b][i] = w2[i%5] . silu(x[b][i]*w1[i%5] + b1[i%5]) + b2[i%5]
// ---------------------------------------------------------------------------
__global__ __launch_bounds__(256)
void basis_kernel(const float* __restrict__ x,
                  const float* __restrict__ w1,
                  const float* __restrict__ b1,
                  const float* __restrict__ w2,
                  const float* __restrict__ b2,
                  __hip_bfloat16* __restrict__ basis) {
    __shared__ float4 pk[K_BASIS][H_DIM + 1];   // {w1,b1,w2,0}
    __shared__ float pb2[K_BASIS];
    const int t = threadIdx.x;
    if (t < K_BASIS * H_DIM) {
        const int k = t / H_DIM, h = t % H_DIM;
        pk[k][h] = float4{w1[t], b1[t], w2[t], 0.f};
        if (t < K_BASIS) pb2[t] = b2[t];
    }
    __syncthreads();

    const int gid = blockIdx.x * 256 + t;
    const int i8 = gid % (I_DIM / 8);
    const int b  = gid / (I_DIM / 8);
    const int i0 = i8 * 8;

    const float4* xp = reinterpret_cast<const float4*>(x + (size_t)b * I_DIM + i0);
    float4 xa = xp[0];
    float4 xb = xp[1];
    float xs[8] = {xa.x, xa.y, xa.z, xa.w, xb.x, xb.y, xb.z, xb.w};

    __hip_bfloat16 res[8];
#pragma unroll
    for (int j = 0; j < 8; ++j) {
        const int idx = (i0 + j) % K_BASIS;
        const float xv = xs[j];
        float acc = 0.f;
#pragma unroll
        for (int h = 0; h < H_DIM; ++h) {
            const float4 p = pk[idx][h];
            float a = fmaf(xv, p.x, p.y);
            float s = a * __builtin_amdgcn_rcpf(1.f + __expf(-a));   // silu
            acc = fmaf(s, p.z, acc);
        }
        res[j] = __float2bfloat16(acc + pb2[idx]);
    }
    *reinterpret_cast<short8*>(basis + (size_t)b * I_DIM + i0) =
        *reinterpret_cast<short8*>(res);
}

// ---------------------------------------------------------------------------
// Kernel 2: out = basis @ Wsum, NO LDS / NO barriers in the main loop.
// Lane (col,kgrp) folds 40 consecutive floats of W row (o0+col) directly
// into its MFMA B-fragment: Wsum[kgrp*8+j][o0+col]. Dual register buffers
// give depth-2 prefetch with counted vmcnt. Each wave = independent
// (o-tile, k-slice); per-WG LDS reduce; partials -> d_ws (no atomics).
// ---------------------------------------------------------------------------
#define NT 16          // o per tile
#define CI 32          // i per chunk (one 16x16x32 k-step)
#define KSPLIT 32      // grid.y; wave k-slices = KSPLIT*4 = 128
#define NC 4           // chunks per wave: 16384/128/32

__global__ __launch_bounds__(256, 3)
void kan_gemm(const float* __restrict__ W,
              const __hip_bfloat16* __restrict__ basis,
              float* __restrict__ P) {
    __shared__ float red[4 * 1024];              // epilogue only (16 KiB)

    const int t    = threadIdx.x;
    const int lane = t & 63;
    const int wv   = t >> 6;
    const int col  = lane & 15;
    const int kgrp = lane >> 4;
    const int o0   = blockIdx.x * NT;
    const int ibase = blockIdx.y * (4 * NC * CI) + wv * (NC * CI);  // wave's 128-i band

    // lane's W source: row o0+col, starting at i = ibase + kgrp*8 (x5 floats)
    const float* const wlane = W + (size_t)(o0 + col) * IK
                                 + (size_t)(ibase + kgrp * 8) * K_BASIS;
    const __hip_bfloat16* const abase = basis + ibase + kgrp * 8;

    float4 ra[10], rb[10];
    short8 afa[4], afb[4];
    f32x4 acc[4] = {f32x4{0,0,0,0}, f32x4{0,0,0,0}, f32x4{0,0,0,0}, f32x4{0,0,0,0}};

#define ISSUE(R, c) do {                                                \
        const float4* p = reinterpret_cast<const float4*>(              \
            wlane + (c) * (CI * K_BASIS));                              \
        _Pragma("unroll") for (int q = 0; q < 10; ++q) R[q] = p[q];     \
    } while (0)

#define AFLOAD(AF, c) do {                                              \
        _Pragma("unroll") for (int m = 0; m < 4; ++m)                   \
            AF[m] = *reinterpret_cast<const short8*>(                   \
                abase + (size_t)(m * 16 + col) * I_DIM + (c) * CI);     \
    } while (0)

#define STEP(R, AF) do {                                                \
        float ws[8] = {0.f,0.f,0.f,0.f,0.f,0.f,0.f,0.f};                \
        _Pragma("unroll") for (int q = 0; q < 10; ++q) {                \
            ws[(4*q+0)/5] += R[q].x;                                    \
            ws[(4*q+1)/5] += R[q].y;                                    \
            ws[(4*q+2)/5] += R[q].z;                                    \
            ws[(4*q+3)/5] += R[q].w;                                    \
        }                                                               \
        __hip_bfloat16 wb8[8];                                          \
        _Pragma("unroll") for (int u = 0; u < 8; ++u)                   \
            wb8[u] = __float2bfloat16(ws[u]);                           \
        const short8 bfr = *reinterpret_cast<short8*>(wb8);             \
        _Pragma("unroll") for (int m = 0; m < 4; ++m)                   \
            acc[m] = __builtin_amdgcn_mfma_f32_16x16x32_bf16(           \
                AF[m], bfr, acc[m], 0, 0, 0);                           \
    } while (0)

    // depth-2 pipeline, fully static buffer names, no barriers
    ISSUE(ra, 0); AFLOAD(afa, 0);
    ISSUE(rb, 1); AFLOAD(afb, 1);
    STEP(ra, afa);                     // chunk 0 (vmcnt leaves rb+afb in flight)
    ISSUE(ra, 2); AFLOAD(afa, 2);
    STEP(rb, afb);                     // chunk 1
    ISSUE(rb, 3); AFLOAD(afb, 3);
    STEP(ra, afa);                     // chunk 2
    STEP(rb, afb);                     // chunk 3

    // ---- epilogue: cross-wave reduce in LDS, float4 store of partial tile ----
#pragma unroll
    for (int m = 0; m < 4; ++m)
#pragma unroll
        for (int j = 0; j < 4; ++j)
            red[wv * 1024 + (m * 16 + kgrp * 4 + j) * 16 + col] = acc[m][j];
    __syncthreads();

    const float4 v0 = *reinterpret_cast<const float4*>(&red[0 * 1024 + t * 4]);
    const float4 v1 = *reinterpret_cast<const float4*>(&red[1 * 1024 + t * 4]);
    const float4 v2 = *reinterpret_cast<const float4*>(&red[2 * 1024 + t * 4]);
    const float4 v3 = *reinterpret_cast<const float4*>(&red[3 * 1024 + t * 4]);
    const float4 s = {v0.x + v1.x + v2.x + v3.x, v0.y + v1.y + v2.y + v3.y,
                      v0.z + v1.z + v2.z + v3.z, v0.w + v1.w + v2.w + v3.w};
    // partial tile: P[(by*64 + bx)][brow][col], flat = brow*16+col = t*4..t*4+3
    *reinterpret_cast<float4*>(
        P + ((size_t)(blockIdx.y * 64 + blockIdx.x) << 10) + t * 4) = s;

#undef ISSUE
#undef AFLOAD
#undef STEP
}

// ---------------------------------------------------------------------------
// Kernel 3: out[b][o] = sum_{g=0..31} P[g*64 + (o>>4)][b][o&15]
// ---------------------------------------------------------------------------
__global__ __launch_bounds__(256)
void reduce_kernel(const float* __restrict__ P, float* __restrict__ out) {
    const int idx = (blockIdx.x * 256 + threadIdx.x) * 4;   // 0..65532
    const int b  = idx >> 10;
    const int o  = idx & 1023;
    const int ox = o >> 4;
    const int c0 = o & 15;

    f32x4 s = {0.f, 0.f, 0.f, 0.f};
#pragma unroll
    for (int g = 0; g < KSPLIT; ++g) {
        const float4 v = *reinterpret_cast<const float4*>(
            P + ((size_t)(g * 64 + ox) << 10) + b * 16 + c0);
        s[0] += v.x; s[1] += v.y; s[2] += v.z; s[3] += v.w;
    }
    *reinterpret_cast<f32x4*>(out + idx) = s;
}

// ---------------------------------------------------------------------------
extern "C" void kernel_launch(void* const* d_in, const int* in_sizes, int n_in,
                              void* d_out, int out_size, void* d_ws, size_t ws_size,
                              hipStream_t stream) {
    const float* x  = (const float*)d_in[0];
    const float* w1 = (const float*)d_in[1];
    const float* b1 = (const float*)d_in[2];
    const float* w2 = (const float*)d_in[3];
    const float* b2 = (const float*)d_in[4];
    const float* W  = (const float*)d_in[5];
    float* out = (float*)d_out;

    __hip_bfloat16* basis = (__hip_bfloat16*)d_ws;                    // 2 MiB
    float* P = (float*)((char*)d_ws + (2 << 20));                     // 8 MiB partials

    basis_kernel<<<dim3((B_DIM * I_DIM / 8) / 256), dim3(256), 0, stream>>>(
        x, w1, b1, w2, b2, basis);

    kan_gemm<<<dim3(O_DIM / NT, KSPLIT), dim3(256), 0, stream>>>(W, basis, P);

    reduce_kernel<<<dim3(B_DIM * O_DIM / 4 / 256), dim3(256), 0, stream>>>(P, out);
}

// Round 8
// 111.521 us; speedup vs baseline: 1.5175x; 1.2883x over previous
//
#include <hip/hip_runtime.h>
#include <hip/hip_bf16.h>

#define B_DIM 64
#define I_DIM 16384
#define O_DIM 1024
#define K_BASIS 5
#define H_DIM 16
#define IK (I_DIM * K_BASIS)   // 81920

typedef __attribute__((ext_vector_type(8))) short short8;
typedef __attribute__((ext_vector_type(4))) float f32x4;

// ---------------------------------------------------------------------------
// Kernel 1: basis[b][i] = w2[i%5] . silu(x[b][i]*w1[i%5] + b1[i%5]) + b2[i%5]
// ---------------------------------------------------------------------------
__global__ __launch_bounds__(256)
void basis_kernel(const float* __restrict__ x,
                  const float* __restrict__ w1,
                  const float* __restrict__ b1,
                  const float* __restrict__ w2,
                  const float* __restrict__ b2,
                  __hip_bfloat16* __restrict__ basis) {
    __shared__ float4 pk[K_BASIS][H_DIM + 1];   // {w1,b1,w2,0}
    __shared__ float pb2[K_BASIS];
    const int t = threadIdx.x;
    if (t < K_BASIS * H_DIM) {
        const int k = t / H_DIM, h = t % H_DIM;
        pk[k][h] = float4{w1[t], b1[t], w2[t], 0.f};
        if (t < K_BASIS) pb2[t] = b2[t];
    }
    __syncthreads();

    const int gid = blockIdx.x * 256 + t;
    const int i8 = gid % (I_DIM / 8);
    const int b  = gid / (I_DIM / 8);
    const int i0 = i8 * 8;

    const float4* xp = reinterpret_cast<const float4*>(x + (size_t)b * I_DIM + i0);
    float4 xa = xp[0];
    float4 xb = xp[1];
    float xs[8] = {xa.x, xa.y, xa.z, xa.w, xb.x, xb.y, xb.z, xb.w};

    __hip_bfloat16 res[8];
#pragma unroll
    for (int j = 0; j < 8; ++j) {
        const int idx = (i0 + j) % K_BASIS;
        const float xv = xs[j];
        float acc = 0.f;
#pragma unroll
        for (int h = 0; h < H_DIM; ++h) {
            const float4 p = pk[idx][h];
            float a = fmaf(xv, p.x, p.y);
            float s = a * __builtin_amdgcn_rcpf(1.f + __expf(-a));   // silu
            acc = fmaf(s, p.z, acc);
        }
        res[j] = __float2bfloat16(acc + pb2[idx]);
    }
    *reinterpret_cast<short8*>(basis + (size_t)b * I_DIM + i0) =
        *reinterpret_cast<short8*>(res);
}

// ---------------------------------------------------------------------------
// Kernel 2 (pass 1): Wsum[g] = sum_{k<5} W[5g+k], bf16 out.
// Dense stream: lane's 5 dwords sit at 20 B stride across the wave -> every
// 64 B granule fully consumed (~20 granules/instr, m13-class). 4 independent
// grid-strided groups per thread for MLP. No LDS, no cross-lane, no barriers.
// ---------------------------------------------------------------------------
#define FOLD_GRID 16384
#define FOLD_STRIDE (FOLD_GRID * 256)   // 4,194,304

__global__ __launch_bounds__(256)
void fold_kernel(const float* __restrict__ W, __hip_bfloat16* __restrict__ Wsum) {
    const int tid = blockIdx.x * 256 + threadIdx.x;
    float s[4];
#pragma unroll
    for (int n = 0; n < 4; ++n) {
        const int g = tid + n * FOLD_STRIDE;
        const float* p = W + (size_t)g * K_BASIS;
        s[n] = ((p[0] + p[1]) + (p[2] + p[3])) + p[4];
    }
#pragma unroll
    for (int n = 0; n < 4; ++n)
        Wsum[tid + n * FOLD_STRIDE] = __float2bfloat16(s[n]);
}

// ---------------------------------------------------------------------------
// Kernel 3 (pass 2): out[64,1024] = basis @ Wsum^T  (both bf16, K=16384).
// Operands are 34 MB total (L2/LLC-class) -> barrier-free depth-2 register
// pipeline per wave; wave = (o-tile 16 rows, 512-i k-slice). r5's proven
// LDS cross-wave reduce + atomicAdd epilogue.
// ---------------------------------------------------------------------------
#define KSPLIT 8
#define NSTEP (I_DIM / KSPLIT / 4 / 32)   // 16 k-steps of 32 per wave

__global__ __launch_bounds__(256)
void gemm2(const __hip_bfloat16* __restrict__ Wsum,
           const __hip_bfloat16* __restrict__ basis,
           float* __restrict__ out) {
    __shared__ float red[4 * 1024];

    const int t    = threadIdx.x;
    const int lane = t & 63;
    const int wv   = t >> 6;
    const int col  = lane & 15;
    const int kgrp = lane >> 4;
    const int o0   = blockIdx.x * 16;
    const int k0   = (blockIdx.y * 4 + wv) * (I_DIM / KSPLIT / 4);  // 512-i band

    const __hip_bfloat16* const bp = Wsum + (size_t)(o0 + col) * I_DIM + k0 + kgrp * 8;
    const __hip_bfloat16* const ap = basis + k0 + kgrp * 8;

    short8 ba, bb, aa[4], ab[4];
    f32x4 acc[4] = {f32x4{0,0,0,0}, f32x4{0,0,0,0}, f32x4{0,0,0,0}, f32x4{0,0,0,0}};

#define LD(BF, AF, c) do {                                              \
        BF = *reinterpret_cast<const short8*>(bp + (c) * 32);           \
        _Pragma("unroll") for (int m = 0; m < 4; ++m)                   \
            AF[m] = *reinterpret_cast<const short8*>(                   \
                ap + (size_t)(m * 16 + col) * I_DIM + (c) * 32);        \
    } while (0)

#define ST(BF, AF) do {                                                 \
        _Pragma("unroll") for (int m = 0; m < 4; ++m)                   \
            acc[m] = __builtin_amdgcn_mfma_f32_16x16x32_bf16(           \
                AF[m], BF, acc[m], 0, 0, 0);                            \
    } while (0)

    LD(ba, aa, 0);
    LD(bb, ab, 1);
#pragma unroll
    for (int c = 0; c < NSTEP - 2; c += 2) {
        ST(ba, aa); LD(ba, aa, c + 2);
        ST(bb, ab); LD(bb, ab, c + 3);
    }
    ST(ba, aa);
    ST(bb, ab);

    // ---- epilogue: cross-wave reduce in LDS, 4 atomics/thread (r5-proven) ----
#pragma unroll
    for (int m = 0; m < 4; ++m)
#pragma unroll
        for (int j = 0; j < 4; ++j)
            red[wv * 1024 + (m * 16 + kgrp * 4 + j) * 16 + col] = acc[m][j];
    __syncthreads();

    const float4 v0 = *reinterpret_cast<const float4*>(&red[0 * 1024 + t * 4]);
    const float4 v1 = *reinterpret_cast<const float4*>(&red[1 * 1024 + t * 4]);
    const float4 v2 = *reinterpret_cast<const float4*>(&red[2 * 1024 + t * 4]);
    const float4 v3 = *reinterpret_cast<const float4*>(&red[3 * 1024 + t * 4]);
    const float s[4] = {v0.x + v1.x + v2.x + v3.x, v0.y + v1.y + v2.y + v3.y,
                        v0.z + v1.z + v2.z + v3.z, v0.w + v1.w + v2.w + v3.w};
    const int brow = t >> 2;
    const int c4   = (t & 3) * 4;
#pragma unroll
    for (int k = 0; k < 4; ++k)
        atomicAdd(&out[(size_t)brow * O_DIM + o0 + c4 + k], s[k]);

#undef LD
#undef ST
}

// ---------------------------------------------------------------------------
extern "C" void kernel_launch(void* const* d_in, const int* in_sizes, int n_in,
                              void* d_out, int out_size, void* d_ws, size_t ws_size,
                              hipStream_t stream) {
    const float* x  = (const float*)d_in[0];
    const float* w1 = (const float*)d_in[1];
    const float* b1 = (const float*)d_in[2];
    const float* w2 = (const float*)d_in[3];
    const float* b2 = (const float*)d_in[4];
    const float* W  = (const float*)d_in[5];
    float* out = (float*)d_out;

    __hip_bfloat16* basis = (__hip_bfloat16*)d_ws;                     // 2 MiB
    __hip_bfloat16* Wsum  = (__hip_bfloat16*)((char*)d_ws + (2 << 20)); // 32 MiB

    hipMemsetAsync(d_out, 0, (size_t)out_size * sizeof(float), stream);

    basis_kernel<<<dim3((B_DIM * I_DIM / 8) / 256), dim3(256), 0, stream>>>(
        x, w1, b1, w2, b2, basis);

    fold_kernel<<<dim3(FOLD_GRID), dim3(256), 0, stream>>>(W, Wsum);

    gemm2<<<dim3(O_DIM / 16, KSPLIT), dim3(256), 0, stream>>>(Wsum, basis, out);
}

// Round 9
// 110.738 us; speedup vs baseline: 1.5282x; 1.0071x over previous
//
#include <hip/hip_runtime.h>
#include <hip/hip_bf16.h>

#define B_DIM 64
#define I_DIM 16384
#define O_DIM 1024
#define K_BASIS 5
#define H_DIM 16
#define IK (I_DIM * K_BASIS)   // 81920

typedef __attribute__((ext_vector_type(8))) short short8;
typedef __attribute__((ext_vector_type(4))) float f32x4;

// ---------------------------------------------------------------------------
// Kernel 1: basis[b][i] = w2[i%5] . silu(x[b][i]*w1[i%5] + b1[i%5]) + b2[i%5]
// ---------------------------------------------------------------------------
__global__ __launch_bounds__(256)
void basis_kernel(const float* __restrict__ x,
                  const float* __restrict__ w1,
                  const float* __restrict__ b1,
                  const float* __restrict__ w2,
                  const float* __restrict__ b2,
                  __hip_bfloat16* __restrict__ basis) {
    __shared__ float4 pk[K_BASIS][H_DIM + 1];   // {w1,b1,w2,0}
    __shared__ float pb2[K_BASIS];
    const int t = threadIdx.x;
    if (t < K_BASIS * H_DIM) {
        const int k = t / H_DIM, h = t % H_DIM;
        pk[k][h] = float4{w1[t], b1[t], w2[t], 0.f};
        if (t < K_BASIS) pb2[t] = b2[t];
    }
    __syncthreads();

    const int gid = blockIdx.x * 256 + t;
    const int i8 = gid % (I_DIM / 8);
    const int b  = gid / (I_DIM / 8);
    const int i0 = i8 * 8;

    const float4* xp = reinterpret_cast<const float4*>(x + (size_t)b * I_DIM + i0);
    float4 xa = xp[0];
    float4 xb = xp[1];
    float xs[8] = {xa.x, xa.y, xa.z, xa.w, xb.x, xb.y, xb.z, xb.w};

    __hip_bfloat16 res[8];
#pragma unroll
    for (int j = 0; j < 8; ++j) {
        const int idx = (i0 + j) % K_BASIS;
        const float xv = xs[j];
        float acc = 0.f;
#pragma unroll
        for (int h = 0; h < H_DIM; ++h) {
            const float4 p = pk[idx][h];
            float a = fmaf(xv, p.x, p.y);
            float s = a * __builtin_amdgcn_rcpf(1.f + __expf(-a));   // silu
            acc = fmaf(s, p.z, acc);
        }
        res[j] = __float2bfloat16(acc + pb2[idx]);
    }
    *reinterpret_cast<short8*>(basis + (size_t)b * I_DIM + i0) =
        *reinterpret_cast<short8*>(res);
}

// ---------------------------------------------------------------------------
// Kernel 2 (pass 1): Wsum[g] = sum_{k<5} W[5g+k], bf16 out.
// INSTRUCTION-DENSE reads (m13-exact): wave-tile = 320 consecutive float2;
// lane l loads W2[T + q*64 + l] (each instr = 512 B contiguous, fully
// consumed). Per-wave LDS redistribute (wave-local, lgkmcnt fence only,
// parity double-buffer, NO barriers), fold in registers, dense 4 B stores.
// 2048 blocks x 20 KiB LDS = 8 blocks/CU, 32 waves/CU.
// ---------------------------------------------------------------------------
#define FOLD_BLOCKS 2048
#define FOLD_WAVES (FOLD_BLOCKS * 4)           // 8192
#define TILE_F2 320                            // float2 per wave-tile (= 128 groups)
#define NTILE (I_DIM * O_DIM / 128 / FOLD_WAVES)   // 16 tiles per wave

__global__ __launch_bounds__(256)
void fold2_kernel(const float* __restrict__ W, __hip_bfloat16* __restrict__ Wsum) {
    __shared__ float2 lds[4][2][TILE_F2];      // per-wave double buffer, 20 KiB
    const int t = threadIdx.x;
    const int l = t & 63;
    const int w = t >> 6;
    const int gwave = blockIdx.x * 4 + w;      // 0..8191

    const float2* __restrict__ W2 = reinterpret_cast<const float2*>(W);

#pragma unroll 1
    for (int it = 0; it < NTILE; ++it) {
        const int tile = gwave + it * FOLD_WAVES;      // grid-stride
        const size_t T = (size_t)tile * TILE_F2;

        float2 v[5];
#pragma unroll
        for (int q = 0; q < 5; ++q) v[q] = W2[T + q * 64 + l];   // lane-dense

        float2* const buf = lds[w][it & 1];
#pragma unroll
        for (int q = 0; q < 5; ++q) buf[q * 64 + l] = v[q];
        asm volatile("s_waitcnt lgkmcnt(0)" ::: "memory");       // wave-local publish

        float2 u[5];
#pragma unroll
        for (int r = 0; r < 5; ++r) u[r] = buf[5 * l + r];       // lane's 2 groups

        const float s0 = ((u[0].x + u[0].y) + (u[1].x + u[1].y)) + u[2].x;
        const float s1 = ((u[2].y + u[3].x) + (u[3].y + u[4].x)) + u[4].y;

        __hip_bfloat162 o2;
        o2.x = __float2bfloat16(s0);
        o2.y = __float2bfloat16(s1);
        *reinterpret_cast<__hip_bfloat162*>(
            Wsum + (size_t)tile * 128 + 2 * l) = o2;             // dense 4 B store
    }
}

// ---------------------------------------------------------------------------
// Kernel 3 (pass 2): out[64,1024] = basis @ Wsum^T  (both bf16, K=16384).
// r8-proven: barrier-free depth-2 register pipeline per wave;
// wave = (o-tile 16 rows, 512-i k-slice); LDS cross-wave reduce + atomics.
// ---------------------------------------------------------------------------
#define KSPLIT 8
#define NSTEP (I_DIM / KSPLIT / 4 / 32)   // 16 k-steps of 32 per wave

__global__ __launch_bounds__(256)
void gemm2(const __hip_bfloat16* __restrict__ Wsum,
           const __hip_bfloat16* __restrict__ basis,
           float* __restrict__ out) {
    __shared__ float red[4 * 1024];

    const int t    = threadIdx.x;
    const int lane = t & 63;
    const int wv   = t >> 6;
    const int col  = lane & 15;
    const int kgrp = lane >> 4;
    const int o0   = blockIdx.x * 16;
    const int k0   = (blockIdx.y * 4 + wv) * (I_DIM / KSPLIT / 4);  // 512-i band

    const __hip_bfloat16* const bp = Wsum + (size_t)(o0 + col) * I_DIM + k0 + kgrp * 8;
    const __hip_bfloat16* const ap = basis + k0 + kgrp * 8;

    short8 ba, bb, aa[4], ab[4];
    f32x4 acc[4] = {f32x4{0,0,0,0}, f32x4{0,0,0,0}, f32x4{0,0,0,0}, f32x4{0,0,0,0}};

#define LD(BF, AF, c) do {                                              \
        BF = *reinterpret_cast<const short8*>(bp + (c) * 32);           \
        _Pragma("unroll") for (int m = 0; m < 4; ++m)                   \
            AF[m] = *reinterpret_cast<const short8*>(                   \
                ap + (size_t)(m * 16 + col) * I_DIM + (c) * 32);        \
    } while (0)

#define ST(BF, AF) do {                                                 \
        _Pragma("unroll") for (int m = 0; m < 4; ++m)                   \
            acc[m] = __builtin_amdgcn_mfma_f32_16x16x32_bf16(           \
                AF[m], BF, acc[m], 0, 0, 0);                            \
    } while (0)

    LD(ba, aa, 0);
    LD(bb, ab, 1);
#pragma unroll
    for (int c = 0; c < NSTEP - 2; c += 2) {
        ST(ba, aa); LD(ba, aa, c + 2);
        ST(bb, ab); LD(bb, ab, c + 3);
    }
    ST(ba, aa);
    ST(bb, ab);

    // ---- epilogue: cross-wave reduce in LDS, 4 atomics/thread ----
#pragma unroll
    for (int m = 0; m < 4; ++m)
#pragma unroll
        for (int j = 0; j < 4; ++j)
            red[wv * 1024 + (m * 16 + kgrp * 4 + j) * 16 + col] = acc[m][j];
    __syncthreads();

    const float4 v0 = *reinterpret_cast<const float4*>(&red[0 * 1024 + t * 4]);
    const float4 v1 = *reinterpret_cast<const float4*>(&red[1 * 1024 + t * 4]);
    const float4 v2 = *reinterpret_cast<const float4*>(&red[2 * 1024 + t * 4]);
    const float4 v3 = *reinterpret_cast<const float4*>(&red[3 * 1024 + t * 4]);
    const float s[4] = {v0.x + v1.x + v2.x + v3.x, v0.y + v1.y + v2.y + v3.y,
                        v0.z + v1.z + v2.z + v3.z, v0.w + v1.w + v2.w + v3.w};
    const int brow = t >> 2;
    const int c4   = (t & 3) * 4;
#pragma unroll
    for (int k = 0; k < 4; ++k)
        atomicAdd(&out[(size_t)brow * O_DIM + o0 + c4 + k], s[k]);

#undef LD
#undef ST
}

// ---------------------------------------------------------------------------
extern "C" void kernel_launch(void* const* d_in, const int* in_sizes, int n_in,
                              void* d_out, int out_size, void* d_ws, size_t ws_size,
                              hipStream_t stream) {
    const float* x  = (const float*)d_in[0];
    const float* w1 = (const float*)d_in[1];
    const float* b1 = (const float*)d_in[2];
    const float* w2 = (const float*)d_in[3];
    const float* b2 = (const float*)d_in[4];
    const float* W  = (const float*)d_in[5];
    float* out = (float*)d_out;

    __hip_bfloat16* basis = (__hip_bfloat16*)d_ws;                      // 2 MiB
    __hip_bfloat16* Wsum  = (__hip_bfloat16*)((char*)d_ws + (2 << 20)); // 32 MiB

    hipMemsetAsync(d_out, 0, (size_t)out_size * sizeof(float), stream);

    basis_kernel<<<dim3((B_DIM * I_DIM / 8) / 256), dim3(256), 0, stream>>>(
        x, w1, b1, w2, b2, basis);

    fold2_kernel<<<dim3(FOLD_BLOCKS), dim3(256), 0, stream>>>(W, Wsum);

    gemm2<<<dim3(O_DIM / 16, KSPLIT), dim3(256), 0, stream>>>(Wsum, basis, out);
}